// Round 12
// baseline (71.345 us; speedup 1.0000x reference)
//
#include <hip/hip_runtime.h>

#define N_NODES 4096
#define BATCH 128
#define SPLITK 16
#define GBN 128                    // GEMM N-tile
#define GBK 32                     // GEMM K-step
#define KCHUNK (N_NODES / SPLITK)  // 256
#define NSTEP (KCHUNK / GBK)       // 8
#define GEMM_BLOCKS ((N_NODES / GBN) * SPLITK)  // 512
#define TRANS_BLOCKS (32 * 32)                  // 128x128 tiles

typedef _Float16 f16x4 __attribute__((ext_vector_type(4)));
typedef _Float16 f16x8 __attribute__((ext_vector_type(8)));
typedef float f32x4 __attribute__((ext_vector_type(4)));
typedef unsigned int u32x4 __attribute__((ext_vector_type(4)));

// ---- async global->LDS DMA (dest = wave-uniform base + lane*16) ----
__device__ __forceinline__ void dma16(const void* g, void* l) {
#if defined(__has_builtin) && __has_builtin(__builtin_amdgcn_global_load_lds)
  __builtin_amdgcn_global_load_lds((const __attribute__((address_space(1))) void*)g,
                                   (__attribute__((address_space(3))) void*)l, 16, 0, 0);
#else
  *(u32x4*)l = *(const u32x4*)g;
#endif
}

// fp8 connT if the HW cvt builtins exist; else bf16 connT.
#if defined(__has_builtin)
#if __has_builtin(__builtin_amdgcn_cvt_f32_fp8) && __has_builtin(__builtin_amdgcn_cvt_pk_fp8_f32)
#define CONN_FP8 1
#endif
#endif
#ifndef CONN_FP8
#define CONN_FP8 0
#endif

#if CONN_FP8
#define CONN_ELEM_BYTES 1
#define CONN_SCALE (1.0f / 256.0f)
#else
#define CONN_ELEM_BYTES 2
#define CONN_SCALE 1.0f
#endif

__device__ __forceinline__ void conn_store4(void* out, size_t off, float4 v) {
#if CONN_FP8
  unsigned int p = __builtin_amdgcn_cvt_pk_fp8_f32(v.x * 256.0f, v.y * 256.0f, 0, false);
  p = (unsigned int)__builtin_amdgcn_cvt_pk_fp8_f32(v.z * 256.0f, v.w * 256.0f, (int)p, true);
  *(unsigned int*)((unsigned char*)out + off) = p;
#else
  const unsigned int ux = __float_as_uint(v.x), uy = __float_as_uint(v.y);
  const unsigned int uz = __float_as_uint(v.z), uw = __float_as_uint(v.w);
  ushort4 u;
  u.x = (unsigned short)((ux + 0x7FFFu + ((ux >> 16) & 1u)) >> 16);  // RNE
  u.y = (unsigned short)((uy + 0x7FFFu + ((uy >> 16) & 1u)) >> 16);
  u.z = (unsigned short)((uz + 0x7FFFu + ((uz >> 16) & 1u)) >> 16);
  u.w = (unsigned short)((uw + 0x7FFFu + ((uw >> 16) & 1u)) >> 16);
  *(ushort4*)((unsigned short*)out + off) = u;
#endif
}

__device__ __forceinline__ float4 conn_load4(const void* cT, int j, int t) {
#if CONN_FP8
  const unsigned int c = *(const unsigned int*)((const unsigned char*)cT + ((size_t)j << 12) + t * 4);
  return make_float4(__builtin_amdgcn_cvt_f32_fp8(c, 0), __builtin_amdgcn_cvt_f32_fp8(c, 1),
                     __builtin_amdgcn_cvt_f32_fp8(c, 2), __builtin_amdgcn_cvt_f32_fp8(c, 3));
#else
  const ushort4 c = *(const ushort4*)((const unsigned short*)cT + ((size_t)j << 12) + t * 4);
  return make_float4(__uint_as_float((unsigned int)c.x << 16),
                     __uint_as_float((unsigned int)c.y << 16),
                     __uint_as_float((unsigned int)c.z << 16),
                     __uint_as_float((unsigned int)c.w << 16));
#endif
}

// ---------------------------------------------------------------------------
// A-split, interleaved: per row m, per 32-k group: (hi[32] | lo[32]) f16,
// pre-scaled x256. Row = 8192 f16 = 16 KB. Also zeroes maxslot.
// ---------------------------------------------------------------------------
__global__ __launch_bounds__(256) void asplit_kernel(const float* __restrict__ in,
                                                     _Float16* __restrict__ As,
                                                     unsigned int* __restrict__ maxslot) {
  if (blockIdx.x == 0 && threadIdx.x == 0) *maxslot = 0u;
  const size_t idx = ((size_t)blockIdx.x * 256 + threadIdx.x) * 4;
  const int m = (int)(idx >> 12);
  const int k = (int)(idx & (N_NODES - 1));
  const float4 v = *(const float4*)(in + idx);
  f16x4 hi, lo;
  const float x0 = v.x * 256.f, x1 = v.y * 256.f, x2 = v.z * 256.f, x3 = v.w * 256.f;
  hi[0] = (_Float16)x0; lo[0] = (_Float16)(x0 - (float)hi[0]);
  hi[1] = (_Float16)x1; lo[1] = (_Float16)(x1 - (float)hi[1]);
  hi[2] = (_Float16)x2; lo[2] = (_Float16)(x2 - (float)hi[2]);
  hi[3] = (_Float16)x3; lo[3] = (_Float16)(x3 - (float)hi[3]);
  const size_t base = (size_t)m * 8192 + (size_t)(k >> 5) * 64 + (k & 31);
  *(f16x4*)(As + base) = hi;
  *(f16x4*)(As + base + 32) = lo;
}

// ---------------------------------------------------------------------------
// Transpose: connT[j][i] = enc(conn[i][j]), 128x128 tiles, full-line writes
// (fp8: 128B/row, bf16: 256B/row). XCD-clustered by 'by' (same conn rows ->
// same XCD's L2). LDS [128][129] f32, 2 blocks/CU.
// ---------------------------------------------------------------------------
__global__ __launch_bounds__(256, 2) void transpose_kernel(const float* __restrict__ conn,
                                                           void* __restrict__ connT) {
  __shared__ float T[128][129];  // 66048 B
  const int tid = threadIdx.x;
  const int d = blockIdx.x;
  const int by = (d & 7) | ((d >> 8) << 3);  // 0..31; d%8 == by%8 -> XCD cluster
  const int bx = (d >> 3) & 31;

  // read: per pass, wave covers 4 rows x 256B contiguous
  const int rr = tid >> 4;          // 0..15
  const int c0 = (tid & 15) * 4;    // 0..60
#pragma unroll
  for (int pass = 0; pass < 8; ++pass) {
    const int r = pass * 16 + rr;
    const float* src = conn + (size_t)(by * 128 + r) * N_NODES + bx * 128;
    const float4 a = *(const float4*)(src + c0);
    const float4 b = *(const float4*)(src + c0 + 64);
    *(float4*)&T[r][c0] = a;
    *(float4*)&T[r][c0 + 64] = b;
  }
  __syncthreads();

  // write: per pass, wave writes 2 out-rows x 128 elems = full lines
  const int jr = tid >> 5;        // 0..7
  const int lc = tid & 31;        // 0..31
#pragma unroll
  for (int pass = 0; pass < 16; ++pass) {
    const int jj = pass * 8 + jr;
    float4 v;
    v.x = T[lc * 4 + 0][jj];
    v.y = T[lc * 4 + 1][jj];
    v.z = T[lc * 4 + 2][jj];
    v.w = T[lc * 4 + 3][jj];
    conn_store4(connT, (size_t)(bx * 128 + jj) * N_NODES + by * 128 + lc * 4, v);
  }
}

// ---------------------------------------------------------------------------
// GEMM (standalone): 128x128 tile, split-f16 3-pass, splitK=16. LDS dbuf +
// global_load_lds DMA + counted vmcnt + both-sides XOR swizzle. T1 XCD
// swizzle: all 16 k-chunks of one n-panel land on one XCD (W panel 2MB -> L2).
// T5 setprio around the MFMA cluster.
// ---------------------------------------------------------------------------
struct GemmSmem {
  alignas(16) _Float16 A[2][128 * 64];  // 2 x 16 KB (hi32|lo32 interleaved rows)
  alignas(16) float B[2][128 * 32];     // 2 x 16 KB (f32 rows)
};  // 64 KB -> 2 blocks/CU

__global__ __launch_bounds__(256, 2) void gemm_kernel(const _Float16* __restrict__ As,
                                                      const float* __restrict__ W,
                                                      float* __restrict__ P) {
  __shared__ GemmSmem sm;
  const int tid = threadIdx.x;
  const int d = blockIdx.x;
  // T1: d%8 == ntile%8 -> all k-chunks of an n-panel share an XCD
  const int ntile = (d & 7) | ((d >> 7) << 3);  // 0..31
  const int kidx = (d >> 3) & 15;               // 0..15
  const int wave = tid >> 6, lane = tid & 63;
  const int wm = wave >> 1, wn = wave & 1;    // 2x2 wave grid, 64x64 each
  const int g = lane >> 4, lrow = lane & 15;  // frag lane coords
  const int n0 = ntile * GBN;
  const int kb = kidx * KCHUNK;
  const int crow = lane >> 3;  // row within 8-row chunk (== row&7)
  const int q = lane & 7;      // 16B granule within 128B row

  // 8 DMAs per wave per issue: 4 A-chunks + 4 B-chunks (1 KB each).
  auto issue = [&](int buf, int t) {
    const size_t abyte = (size_t)((kb >> 5) + t) * 128;  // A row: 16KB, 128B/group
    const size_t bbyte = (size_t)(kb + t * GBK) * 4;     // W row: 16KB f32
#pragma unroll
    for (int i = 0; i < 4; ++i) {
      const int c = wave * 4 + i;    // 0..15
      const int row = c * 8 + crow;  // 0..127
      dma16((const char*)As + (size_t)row * 16384 + abyte + ((q ^ crow) << 4),
            (char*)sm.A[buf] + c * 1024 + lane * 16);
    }
#pragma unroll
    for (int i = 0; i < 4; ++i) {
      const int c = wave * 4 + i;
      const int row = c * 8 + crow;
      dma16((const char*)W + (size_t)(n0 + row) * 16384 + bbyte + ((q ^ crow) << 4),
            (char*)sm.B[buf] + c * 1024 + lane * 16);
    }
  };

  f32x4 acc[4][4] = {};
  issue(0, 0);
  issue(1, 1);

#pragma unroll
  for (int t = 0; t < NSTEP; ++t) {
    const int cur = t & 1;
    // Counted drain: tile t landed; tile t+1's 8 DMAs stay in flight.
    if (t + 1 < NSTEP) asm volatile("s_waitcnt vmcnt(8)" ::: "memory");
    else               asm volatile("s_waitcnt vmcnt(0)" ::: "memory");
    __builtin_amdgcn_sched_barrier(0);
    __builtin_amdgcn_s_barrier();
    __builtin_amdgcn_sched_barrier(0);

    // A frags: granule g = hi k[g*8..+8), granule 4+g = lo
    f16x8 ah[4], al[4];
#pragma unroll
    for (int fm = 0; fm < 4; ++fm) {
      const int mr = wm * 64 + fm * 16 + lrow;
      const char* ab = (const char*)sm.A[cur] + mr * 128;
      const int s = (mr & 7) << 4;
      ah[fm] = *(const f16x8*)(ab + ((g << 4) ^ s));
      al[fm] = *(const f16x8*)(ab + (((4 + g) << 4) ^ s));
    }
    // B frags: 8 f32 at granules 2g,2g+1 -> consumer-side hi/lo split (x64)
    f16x8 bh[4], bl[4];
#pragma unroll
    for (int fn = 0; fn < 4; ++fn) {
      const int nr = wn * 64 + fn * 16 + lrow;
      const char* bb = (const char*)sm.B[cur] + nr * 128;
      const int s = (nr & 7) << 4;
      const f32x4 b0 = *(const f32x4*)(bb + (((2 * g) << 4) ^ s));
      const f32x4 b1 = *(const f32x4*)(bb + (((2 * g + 1) << 4) ^ s));
#pragma unroll
      for (int j = 0; j < 4; ++j) {
        const float x = b0[j] * 64.f;
        const _Float16 h = (_Float16)x;
        bh[fn][j] = h; bl[fn][j] = (_Float16)(x - (float)h);
        const float y = b1[j] * 64.f;
        const _Float16 h2 = (_Float16)y;
        bh[fn][4 + j] = h2; bl[fn][4 + j] = (_Float16)(y - (float)h2);
      }
    }
    __builtin_amdgcn_s_setprio(1);
#pragma unroll
    for (int fm = 0; fm < 4; ++fm)
#pragma unroll
      for (int fn = 0; fn < 4; ++fn) {
        acc[fm][fn] = __builtin_amdgcn_mfma_f32_16x16x32_f16(ah[fm], bh[fn], acc[fm][fn], 0, 0, 0);
        acc[fm][fn] = __builtin_amdgcn_mfma_f32_16x16x32_f16(ah[fm], bl[fn], acc[fm][fn], 0, 0, 0);
        acc[fm][fn] = __builtin_amdgcn_mfma_f32_16x16x32_f16(al[fm], bh[fn], acc[fm][fn], 0, 0, 0);
      }
    __builtin_amdgcn_s_setprio(0);

    __builtin_amdgcn_sched_barrier(0);
    __builtin_amdgcn_s_barrier();  // all waves done reading buf cur
    __builtin_amdgcn_sched_barrier(0);
    if (t + 2 < NSTEP) issue(cur, t + 2);
  }

  // epilogue: D row = (lane>>4)*4 + reg, col = lane&15 (HW-verified)
  constexpr float INV = 1.0f / 16384.0f;  // 1/(256*64)
  float* Pb = P + (size_t)kidx * BATCH * N_NODES;
#pragma unroll
  for (int fm = 0; fm < 4; ++fm)
#pragma unroll
    for (int fn = 0; fn < 4; ++fn) {
      const int n = n0 + wn * 64 + fn * 16 + lrow;
#pragma unroll
      for (int reg = 0; reg < 4; ++reg) {
        const int m = wm * 64 + fm * 16 + g * 4 + reg;
        Pb[(size_t)m * N_NODES + n] = acc[fm][fn][reg] * INV;
      }
    }
}

// ---------------------------------------------------------------------------
// Fallback-only f32 VALU GEMM (no workspace)
// ---------------------------------------------------------------------------
__global__ __launch_bounds__(256) void proj_gemm_valu(const float* __restrict__ A,
                                                      const float* __restrict__ W,
                                                      float* __restrict__ P,
                                                      unsigned int* __restrict__ maxslot) {
  if (blockIdx.x == 0 && threadIdx.x == 0) *maxslot = 0u;
  __shared__ float Asb[16][132];
  __shared__ float Bsb[16][68];
  const int tid = threadIdx.x;
  const int n0 = blockIdx.x * 64;
  const int tx = tid & 15, ty = tid >> 4;
  const int arow = tid >> 1, acol = (tid & 1) * 8;
  const int brow = tid >> 2, bcol = (tid & 3) * 4;
  float acc[2][4][4] = {};
  const float* Aptr = A + (size_t)arow * N_NODES + acol;
  const float* Wptr = W + (size_t)(n0 + brow) * N_NODES + bcol;
  for (int k0 = 0; k0 < N_NODES; k0 += 16) {
    const float4 a0 = *(const float4*)(Aptr + k0);
    const float4 a1 = *(const float4*)(Aptr + k0 + 4);
    const float4 bv = *(const float4*)(Wptr + k0);
    __syncthreads();
    Asb[acol + 0][arow] = a0.x; Asb[acol + 1][arow] = a0.y;
    Asb[acol + 2][arow] = a0.z; Asb[acol + 3][arow] = a0.w;
    Asb[acol + 4][arow] = a1.x; Asb[acol + 5][arow] = a1.y;
    Asb[acol + 6][arow] = a1.z; Asb[acol + 7][arow] = a1.w;
    Bsb[bcol + 0][brow] = bv.x; Bsb[bcol + 1][brow] = bv.y;
    Bsb[bcol + 2][brow] = bv.z; Bsb[bcol + 3][brow] = bv.w;
    __syncthreads();
#pragma unroll
    for (int kk = 0; kk < 16; ++kk) {
      const float4 av0 = *(const float4*)&Asb[kk][ty * 4];
      const float4 av1 = *(const float4*)&Asb[kk][64 + ty * 4];
      const float4 bv4 = *(const float4*)&Bsb[kk][tx * 4];
      const float am[8] = {av0.x, av0.y, av0.z, av0.w, av1.x, av1.y, av1.z, av1.w};
      const float bn[4] = {bv4.x, bv4.y, bv4.z, bv4.w};
#pragma unroll
      for (int i2 = 0; i2 < 2; ++i2)
#pragma unroll
        for (int i = 0; i < 4; ++i)
#pragma unroll
          for (int j = 0; j < 4; ++j)
            acc[i2][i][j] += am[i2 * 4 + i] * bn[j];
    }
  }
#pragma unroll
  for (int i2 = 0; i2 < 2; ++i2)
#pragma unroll
    for (int i = 0; i < 4; ++i) {
      const int m = i2 * 64 + ty * 4 + i;
      *(float4*)(P + (size_t)m * N_NODES + n0 + tx * 4) =
          make_float4(acc[i2][i][0], acc[i2][i][1], acc[i2][i][2], acc[i2][i][3]);
    }
}

__global__ __launch_bounds__(256) void bias_inplace_kernel(float* __restrict__ P,
                                                           const float* __restrict__ bias) {
  const size_t base = ((size_t)blockIdx.x * 256 + threadIdx.x) * 4;
  const int n = (int)(base & (N_NODES - 1));
  float4 s = *(const float4*)(P + base);
  const float4 bv = *(const float4*)(bias + n);
  s.x += bv.x; s.y += bv.y; s.z += bv.z; s.w += bv.w;
  *(float4*)(P + base) = s;
}

// ---------------------------------------------------------------------------
// Avalanche: one workgroup per sample; state in registers.
// ---------------------------------------------------------------------------
template <int MODE, int NSPLIT>
__global__ __launch_bounds__(1024) void avalanche_kernel(const float* __restrict__ Pin,
                                                         const float* __restrict__ bias,
                                                         const void* __restrict__ connv,
                                                         float* __restrict__ out,
                                                         unsigned int* __restrict__ maxslot) {
  const int b = blockIdx.x;
  const int t = threadIdx.x;
  __shared__ unsigned long long mask[64];
  __shared__ int wincl[64];
  __shared__ int list[N_NODES];

  float4 s;
  if (MODE == 1) {
    const float4 bv = *(const float4*)(bias + t * 4);
    s = bv;
#pragma unroll
    for (int sp = 0; sp < NSPLIT; ++sp) {
      const float4 v = *(const float4*)(Pin + (size_t)sp * BATCH * N_NODES +
                                        (size_t)b * N_NODES + t * 4);
      s.x += v.x; s.y += v.y; s.z += v.z; s.w += v.w;
    }
  } else {
    s = *(const float4*)(Pin + (size_t)b * N_NODES + t * 4);
  }

  float total = 0.0f;

  for (int it = 0; it < 100; ++it) {
    const float v0 = s.x, v1 = s.y, v2 = s.z, v3 = s.w;
    unsigned int bits = 0;
    if (v0 > 1.0f) bits |= 1u;
    if (v1 > 1.0f) bits |= 2u;
    if (v2 > 1.0f) bits |= 4u;
    if (v3 > 1.0f) bits |= 8u;

    __syncthreads();
    if (t < 64) mask[t] = 0ULL;
    __syncthreads();
    if (bits) atomicOr(&mask[t >> 4], (unsigned long long)bits << ((t & 15) * 4));
    __syncthreads();

    if (t < 64) {
      int incl = __popcll(mask[t]);
#pragma unroll
      for (int d = 1; d < 64; d <<= 1) {
        const int y = __shfl_up(incl, d);
        if (t >= d) incl += y;
      }
      wincl[t] = incl;
    }
    __syncthreads();
    const int n = wincl[63];
    if (n == 0) break;  // sticky done: state frozen
    total += (float)n;

    if (t < 64) {
      unsigned long long m = mask[t];
      int o = wincl[t] - __popcll(m);
      while (m) {
        list[o++] = (t << 6) + __builtin_ctzll(m);
        m &= m - 1;
      }
    }
    __syncthreads();

    float4 a0 = make_float4(0.f, 0.f, 0.f, 0.f), a1 = a0, a2 = a0, a3 = a0;
    if (MODE == 1) {
      int idx = 0;
      for (; idx + 8 <= n; idx += 8) {
        const float4 c0 = conn_load4(connv, list[idx + 0], t);
        const float4 c1 = conn_load4(connv, list[idx + 1], t);
        const float4 c2 = conn_load4(connv, list[idx + 2], t);
        const float4 c3 = conn_load4(connv, list[idx + 3], t);
        const float4 c4 = conn_load4(connv, list[idx + 4], t);
        const float4 c5 = conn_load4(connv, list[idx + 5], t);
        const float4 c6 = conn_load4(connv, list[idx + 6], t);
        const float4 c7 = conn_load4(connv, list[idx + 7], t);
        a0.x += c0.x; a0.y += c0.y; a0.z += c0.z; a0.w += c0.w;
        a1.x += c1.x; a1.y += c1.y; a1.z += c1.z; a1.w += c1.w;
        a2.x += c2.x; a2.y += c2.y; a2.z += c2.z; a2.w += c2.w;
        a3.x += c3.x; a3.y += c3.y; a3.z += c3.z; a3.w += c3.w;
        a0.x += c4.x; a0.y += c4.y; a0.z += c4.z; a0.w += c4.w;
        a1.x += c5.x; a1.y += c5.y; a1.z += c5.z; a1.w += c5.w;
        a2.x += c6.x; a2.y += c6.y; a2.z += c6.z; a2.w += c6.w;
        a3.x += c7.x; a3.y += c7.y; a3.z += c7.z; a3.w += c7.w;
      }
      for (; idx < n; ++idx) {
        const float4 c = conn_load4(connv, list[idx], t);
        a0.x += c.x; a0.y += c.y; a0.z += c.z; a0.w += c.w;
      }
    } else {
      const float* conn = (const float*)connv;
      for (int idx = 0; idx < n; ++idx) {
        const int j = list[idx];
        a0.x += conn[(size_t)(t * 4 + 0) * N_NODES + j];
        a0.y += conn[(size_t)(t * 4 + 1) * N_NODES + j];
        a0.z += conn[(size_t)(t * 4 + 2) * N_NODES + j];
        a0.w += conn[(size_t)(t * 4 + 3) * N_NODES + j];
      }
    }
    const float sc = (MODE == 1) ? CONN_SCALE : 1.0f;
    const float4 acc = make_float4(((a0.x + a1.x) + (a2.x + a3.x)) * sc,
                                   ((a0.y + a1.y) + (a2.y + a3.y)) * sc,
                                   ((a0.z + a1.z) + (a2.z + a3.z)) * sc,
                                   ((a0.w + a1.w) + (a2.w + a3.w)) * sc);

    s.x = (v0 > 1.0f) ? 0.0f : 0.9f * v0 + acc.x;
    s.y = (v1 > 1.0f) ? 0.0f : 0.9f * v1 + acc.y;
    s.z = (v2 > 1.0f) ? 0.0f : 0.9f * v2 + acc.z;
    s.w = (v3 > 1.0f) ? 0.0f : 0.9f * v3 + acc.w;
  }

  *(float4*)(out + (size_t)b * N_NODES + t * 4) = s;
  if (t == 0) atomicMax(maxslot, __float_as_uint(total));  // totals >= 0
}

// ---------------------------------------------------------------------------
extern "C" void kernel_launch(void* const* d_in, const int* in_sizes, int n_in,
                              void* d_out, int out_size, void* d_ws, size_t ws_size,
                              hipStream_t stream) {
  const float* input = (const float*)d_in[0];  // [128,4096]
  const float* W     = (const float*)d_in[1];  // [4096,4096]
  const float* bias  = (const float*)d_in[2];  // [4096]
  const float* conn  = (const float*)d_in[3];  // [4096,4096]
  float* out = (float*)d_out;                  // [128*4096] state + [1] max_size

  const size_t aplane_bytes = (size_t)BATCH * N_NODES * 4;                       // 2 MB interleaved
  const size_t connT_bytes  = (size_t)N_NODES * N_NODES * CONN_ELEM_BYTES;       // 16/32 MB
  const size_t part_bytes   = (size_t)SPLITK * BATCH * N_NODES * sizeof(float);  // 32 MB
  unsigned int* maxslot = (unsigned int*)(out + (size_t)BATCH * N_NODES);

  if (ws_size >= aplane_bytes + connT_bytes + part_bytes) {
    _Float16* As = (_Float16*)d_ws;
    void* connT  = (char*)d_ws + aplane_bytes;
    float* part  = (float*)((char*)d_ws + aplane_bytes + connT_bytes);
    asplit_kernel<<<BATCH * N_NODES / 1024, 256, 0, stream>>>(input, As, maxslot);
    transpose_kernel<<<TRANS_BLOCKS, 256, 0, stream>>>(conn, connT);
    gemm_kernel<<<GEMM_BLOCKS, 256, 0, stream>>>(As, W, part);
    avalanche_kernel<1, SPLITK><<<BATCH, 1024, 0, stream>>>(part, bias, connT, out, maxslot);
  } else {
    // Fallback: no workspace — f32 GEMM into d_out, in-place bias, strided gather.
    proj_gemm_valu<<<dim3(N_NODES / 64, 1), 256, 0, stream>>>(input, W, out, maxslot);
    bias_inplace_kernel<<<BATCH * N_NODES / 1024, 256, 0, stream>>>(out, bias);
    avalanche_kernel<0, 1><<<BATCH, 1024, 0, stream>>>(out, nullptr, conn, out, maxslot);
  }
}

// Round 13
// 71.191 us; speedup vs baseline: 1.0022x; 1.0022x over previous
//
#include <hip/hip_runtime.h>

#define N_NODES 4096
#define BATCH 128
#define SPLITK 16
#define GBN 64                     // GEMM N-tile
#define GBK 32                     // GEMM K-step
#define KCHUNK (N_NODES / SPLITK)  // 256
#define NSTEP (KCHUNK / GBK)       // 8
#define GEMM_BLOCKS ((N_NODES / GBN) * SPLITK)  // 1024
#define TRANS_BLOCKS (32 * 32)                  // 128x128 tiles

typedef _Float16 f16x4 __attribute__((ext_vector_type(4)));
typedef _Float16 f16x8 __attribute__((ext_vector_type(8)));
typedef float f32x4 __attribute__((ext_vector_type(4)));
typedef unsigned int u32x4 __attribute__((ext_vector_type(4)));

// ---- async global->LDS DMA (dest = wave-uniform base + lane*16) ----
__device__ __forceinline__ void dma16(const void* g, void* l) {
#if defined(__has_builtin) && __has_builtin(__builtin_amdgcn_global_load_lds)
  __builtin_amdgcn_global_load_lds((const __attribute__((address_space(1))) void*)g,
                                   (__attribute__((address_space(3))) void*)l, 16, 0, 0);
#else
  *(u32x4*)l = *(const u32x4*)g;
#endif
}

// fp8 connT if the HW cvt builtins exist; else bf16 connT.
#if defined(__has_builtin)
#if __has_builtin(__builtin_amdgcn_cvt_f32_fp8) && __has_builtin(__builtin_amdgcn_cvt_pk_fp8_f32)
#define CONN_FP8 1
#endif
#endif
#ifndef CONN_FP8
#define CONN_FP8 0
#endif

#if CONN_FP8
#define CONN_ELEM_BYTES 1
#define CONN_SCALE (1.0f / 256.0f)
#else
#define CONN_ELEM_BYTES 2
#define CONN_SCALE 1.0f
#endif

__device__ __forceinline__ void conn_store4(void* out, size_t off, float4 v) {
#if CONN_FP8
  unsigned int p = __builtin_amdgcn_cvt_pk_fp8_f32(v.x * 256.0f, v.y * 256.0f, 0, false);
  p = (unsigned int)__builtin_amdgcn_cvt_pk_fp8_f32(v.z * 256.0f, v.w * 256.0f, (int)p, true);
  *(unsigned int*)((unsigned char*)out + off) = p;
#else
  const unsigned int ux = __float_as_uint(v.x), uy = __float_as_uint(v.y);
  const unsigned int uz = __float_as_uint(v.z), uw = __float_as_uint(v.w);
  ushort4 u;
  u.x = (unsigned short)((ux + 0x7FFFu + ((ux >> 16) & 1u)) >> 16);  // RNE
  u.y = (unsigned short)((uy + 0x7FFFu + ((uy >> 16) & 1u)) >> 16);
  u.z = (unsigned short)((uz + 0x7FFFu + ((uz >> 16) & 1u)) >> 16);
  u.w = (unsigned short)((uw + 0x7FFFu + ((uw >> 16) & 1u)) >> 16);
  *(ushort4*)((unsigned short*)out + off) = u;
#endif
}

__device__ __forceinline__ float4 conn_load4(const void* cT, int j, int t) {
#if CONN_FP8
  const unsigned int c = *(const unsigned int*)((const unsigned char*)cT + ((size_t)j << 12) + t * 4);
  return make_float4(__builtin_amdgcn_cvt_f32_fp8(c, 0), __builtin_amdgcn_cvt_f32_fp8(c, 1),
                     __builtin_amdgcn_cvt_f32_fp8(c, 2), __builtin_amdgcn_cvt_f32_fp8(c, 3));
#else
  const ushort4 c = *(const ushort4*)((const unsigned short*)cT + ((size_t)j << 12) + t * 4);
  return make_float4(__uint_as_float((unsigned int)c.x << 16),
                     __uint_as_float((unsigned int)c.y << 16),
                     __uint_as_float((unsigned int)c.z << 16),
                     __uint_as_float((unsigned int)c.w << 16));
#endif
}

// ---------------------------------------------------------------------------
// A-split, interleaved: per row m, per 32-k group: (hi[32] | lo[32]) f16,
// pre-scaled x256. Row = 8192 f16 = 16 KB. Also zeroes maxslot.
// ---------------------------------------------------------------------------
__global__ __launch_bounds__(256) void asplit_kernel(const float* __restrict__ in,
                                                     _Float16* __restrict__ As,
                                                     unsigned int* __restrict__ maxslot) {
  if (blockIdx.x == 0 && threadIdx.x == 0) *maxslot = 0u;
  const size_t idx = ((size_t)blockIdx.x * 256 + threadIdx.x) * 4;
  const int m = (int)(idx >> 12);
  const int k = (int)(idx & (N_NODES - 1));
  const float4 v = *(const float4*)(in + idx);
  f16x4 hi, lo;
  const float x0 = v.x * 256.f, x1 = v.y * 256.f, x2 = v.z * 256.f, x3 = v.w * 256.f;
  hi[0] = (_Float16)x0; lo[0] = (_Float16)(x0 - (float)hi[0]);
  hi[1] = (_Float16)x1; lo[1] = (_Float16)(x1 - (float)hi[1]);
  hi[2] = (_Float16)x2; lo[2] = (_Float16)(x2 - (float)hi[2]);
  hi[3] = (_Float16)x3; lo[3] = (_Float16)(x3 - (float)hi[3]);
  const size_t base = (size_t)m * 8192 + (size_t)(k >> 5) * 64 + (k & 31);
  *(f16x4*)(As + base) = hi;
  *(f16x4*)(As + base + 32) = lo;
}

// ---------------------------------------------------------------------------
// Transpose: connT[j][i] = enc(conn[i][j]), 128x128 tiles, full-line writes.
// ---------------------------------------------------------------------------
__global__ __launch_bounds__(256, 2) void transpose_kernel(const float* __restrict__ conn,
                                                           void* __restrict__ connT) {
  __shared__ float T[128][129];  // 66048 B
  const int tid = threadIdx.x;
  const int d = blockIdx.x;
  const int by = (d & 7) | ((d >> 8) << 3);  // XCD cluster on source rows
  const int bx = (d >> 3) & 31;

  const int rr = tid >> 4;        // 0..15
  const int c0 = (tid & 15) * 4;  // 0..60
#pragma unroll
  for (int pass = 0; pass < 8; ++pass) {
    const int r = pass * 16 + rr;
    const float* src = conn + (size_t)(by * 128 + r) * N_NODES + bx * 128;
    const float4 a = *(const float4*)(src + c0);
    const float4 b = *(const float4*)(src + c0 + 64);
    *(float4*)&T[r][c0] = a;
    *(float4*)&T[r][c0 + 64] = b;
  }
  __syncthreads();

  const int jr = tid >> 5;  // 0..7
  const int lc = tid & 31;  // 0..31
#pragma unroll
  for (int pass = 0; pass < 16; ++pass) {
    const int jj = pass * 8 + jr;
    float4 v;
    v.x = T[lc * 4 + 0][jj];
    v.y = T[lc * 4 + 1][jj];
    v.z = T[lc * 4 + 2][jj];
    v.w = T[lc * 4 + 3][jj];
    conn_store4(connT, (size_t)(bx * 128 + jj) * N_NODES + by * 128 + lc * 4, v);
  }
}

// ---------------------------------------------------------------------------
// GEMM: 128x64 tile, split-f16 3-pass, splitK=16 -> grid 1024 (4+ blocks/CU).
// SINGLE-buffered 24 KB LDS, plain __syncthreads — cross-block wave overlap
// (m97/m114 mechanism) hides the per-step drain instead of in-block vmcnt.
// XCD mapping: kidx = bid&15 -> each XCD owns 2 A k-slices (L2-hot).
// ---------------------------------------------------------------------------
struct GemmSmem {
  alignas(16) _Float16 A[128 * 64];  // 16 KB (hi32|lo32 interleaved rows, 128B/row)
  alignas(16) float B[GBN * 32];     // 8 KB (f32 rows, 128B/row)
};  // 24 KB -> up to 6 blocks/CU

__global__ __launch_bounds__(256, 4) void gemm_kernel(const _Float16* __restrict__ As,
                                                      const float* __restrict__ W,
                                                      float* __restrict__ P) {
  __shared__ GemmSmem sm;
  const int tid = threadIdx.x;
  const int bid = blockIdx.x;
  const int kidx = bid & 15;   // same-k blocks spread 2-per-XCD -> A slice L2-hot
  const int ntile = bid >> 4;  // 0..63
  const int wave = tid >> 6, lane = tid & 63;
  const int wm = wave >> 1, wn = wave & 1;    // 2x2 wave grid: 64 rows x 32 cols
  const int g = lane >> 4, lrow = lane & 15;  // frag lane coords
  const int n0 = ntile * GBN;
  const int kb = kidx * KCHUNK;
  const int crow = lane >> 3;  // row within 8-row chunk (== row&7)
  const int q = lane & 7;      // 16B granule within 128B row

  // 6 DMAs per wave per step: 4 A-chunks + 2 B-chunks (1 KB each).
  auto issue = [&](int t) {
    const size_t abyte = (size_t)((kb >> 5) + t) * 128;  // A row 16KB, 128B per 32k
    const size_t bbyte = (size_t)(kb + t * GBK) * 4;     // W row 16KB f32
#pragma unroll
    for (int i = 0; i < 4; ++i) {
      const int c = wave * 4 + i;    // 0..15
      const int row = c * 8 + crow;  // 0..127
      dma16((const char*)As + (size_t)row * 16384 + abyte + ((q ^ crow) << 4),
            (char*)sm.A + c * 1024 + lane * 16);
    }
#pragma unroll
    for (int i = 0; i < 2; ++i) {
      const int c = wave * 2 + i;    // 0..7
      const int row = c * 8 + crow;  // 0..63
      dma16((const char*)W + (size_t)(n0 + row) * 16384 + bbyte + ((q ^ crow) << 4),
            (char*)sm.B + c * 1024 + lane * 16);
    }
  };

  f32x4 acc[4][2] = {};

#pragma unroll
  for (int t = 0; t < NSTEP; ++t) {
    issue(t);
    __syncthreads();  // drains DMAs; other resident blocks cover the stall

    // A frags: granule g = hi k[g*8..+8), granule 4+g = lo
    f16x8 ah[4], al[4];
#pragma unroll
    for (int fm = 0; fm < 4; ++fm) {
      const int mr = wm * 64 + fm * 16 + lrow;
      const char* ab = (const char*)sm.A + mr * 128;
      const int s = (mr & 7) << 4;
      ah[fm] = *(const f16x8*)(ab + ((g << 4) ^ s));
      al[fm] = *(const f16x8*)(ab + (((4 + g) << 4) ^ s));
    }
    // B frags: 8 f32 at granules 2g,2g+1 -> consumer-side hi/lo split (x64)
    f16x8 bh[2], bl[2];
#pragma unroll
    for (int fn = 0; fn < 2; ++fn) {
      const int nr = wn * 32 + fn * 16 + lrow;
      const char* bb = (const char*)sm.B + nr * 128;
      const int s = (nr & 7) << 4;
      const f32x4 b0 = *(const f32x4*)(bb + (((2 * g) << 4) ^ s));
      const f32x4 b1 = *(const f32x4*)(bb + (((2 * g + 1) << 4) ^ s));
#pragma unroll
      for (int j = 0; j < 4; ++j) {
        const float x = b0[j] * 64.f;
        const _Float16 h = (_Float16)x;
        bh[fn][j] = h; bl[fn][j] = (_Float16)(x - (float)h);
        const float y = b1[j] * 64.f;
        const _Float16 h2 = (_Float16)y;
        bh[fn][4 + j] = h2; bl[fn][4 + j] = (_Float16)(y - (float)h2);
      }
    }
#pragma unroll
    for (int fm = 0; fm < 4; ++fm)
#pragma unroll
      for (int fn = 0; fn < 2; ++fn) {
        acc[fm][fn] = __builtin_amdgcn_mfma_f32_16x16x32_f16(ah[fm], bh[fn], acc[fm][fn], 0, 0, 0);
        acc[fm][fn] = __builtin_amdgcn_mfma_f32_16x16x32_f16(ah[fm], bl[fn], acc[fm][fn], 0, 0, 0);
        acc[fm][fn] = __builtin_amdgcn_mfma_f32_16x16x32_f16(al[fm], bh[fn], acc[fm][fn], 0, 0, 0);
      }
    __syncthreads();  // all waves done reading before next step's DMA overwrites
  }

  // epilogue: D row = (lane>>4)*4 + reg, col = lane&15 (HW-verified)
  constexpr float INV = 1.0f / 16384.0f;  // 1/(256*64)
  float* Pb = P + (size_t)kidx * BATCH * N_NODES;
#pragma unroll
  for (int fm = 0; fm < 4; ++fm)
#pragma unroll
    for (int fn = 0; fn < 2; ++fn) {
      const int n = n0 + wn * 32 + fn * 16 + lrow;
#pragma unroll
      for (int reg = 0; reg < 4; ++reg) {
        const int m = wm * 64 + fm * 16 + g * 4 + reg;
        Pb[(size_t)m * N_NODES + n] = acc[fm][fn][reg] * INV;
      }
    }
}

// ---------------------------------------------------------------------------
// Fallback-only f32 VALU GEMM (no workspace)
// ---------------------------------------------------------------------------
__global__ __launch_bounds__(256) void proj_gemm_valu(const float* __restrict__ A,
                                                      const float* __restrict__ W,
                                                      float* __restrict__ P,
                                                      unsigned int* __restrict__ maxslot) {
  if (blockIdx.x == 0 && threadIdx.x == 0) *maxslot = 0u;
  __shared__ float Asb[16][132];
  __shared__ float Bsb[16][68];
  const int tid = threadIdx.x;
  const int n0 = blockIdx.x * 64;
  const int tx = tid & 15, ty = tid >> 4;
  const int arow = tid >> 1, acol = (tid & 1) * 8;
  const int brow = tid >> 2, bcol = (tid & 3) * 4;
  float acc[2][4][4] = {};
  const float* Aptr = A + (size_t)arow * N_NODES + acol;
  const float* Wptr = W + (size_t)(n0 + brow) * N_NODES + bcol;
  for (int k0 = 0; k0 < N_NODES; k0 += 16) {
    const float4 a0 = *(const float4*)(Aptr + k0);
    const float4 a1 = *(const float4*)(Aptr + k0 + 4);
    const float4 bv = *(const float4*)(Wptr + k0);
    __syncthreads();
    Asb[acol + 0][arow] = a0.x; Asb[acol + 1][arow] = a0.y;
    Asb[acol + 2][arow] = a0.z; Asb[acol + 3][arow] = a0.w;
    Asb[acol + 4][arow] = a1.x; Asb[acol + 5][arow] = a1.y;
    Asb[acol + 6][arow] = a1.z; Asb[acol + 7][arow] = a1.w;
    Bsb[bcol + 0][brow] = bv.x; Bsb[bcol + 1][brow] = bv.y;
    Bsb[bcol + 2][brow] = bv.z; Bsb[bcol + 3][brow] = bv.w;
    __syncthreads();
#pragma unroll
    for (int kk = 0; kk < 16; ++kk) {
      const float4 av0 = *(const float4*)&Asb[kk][ty * 4];
      const float4 av1 = *(const float4*)&Asb[kk][64 + ty * 4];
      const float4 bv4 = *(const float4*)&Bsb[kk][tx * 4];
      const float am[8] = {av0.x, av0.y, av0.z, av0.w, av1.x, av1.y, av1.z, av1.w};
      const float bn[4] = {bv4.x, bv4.y, bv4.z, bv4.w};
#pragma unroll
      for (int i2 = 0; i2 < 2; ++i2)
#pragma unroll
        for (int i = 0; i < 4; ++i)
#pragma unroll
          for (int j = 0; j < 4; ++j)
            acc[i2][i][j] += am[i2 * 4 + i] * bn[j];
    }
  }
#pragma unroll
  for (int i2 = 0; i2 < 2; ++i2)
#pragma unroll
    for (int i = 0; i < 4; ++i) {
      const int m = i2 * 64 + ty * 4 + i;
      *(float4*)(P + (size_t)m * N_NODES + n0 + tx * 4) =
          make_float4(acc[i2][i][0], acc[i2][i][1], acc[i2][i][2], acc[i2][i][3]);
    }
}

__global__ __launch_bounds__(256) void bias_inplace_kernel(float* __restrict__ P,
                                                           const float* __restrict__ bias) {
  const size_t base = ((size_t)blockIdx.x * 256 + threadIdx.x) * 4;
  const int n = (int)(base & (N_NODES - 1));
  float4 s = *(const float4*)(P + base);
  const float4 bv = *(const float4*)(bias + n);
  s.x += bv.x; s.y += bv.y; s.z += bv.z; s.w += bv.w;
  *(float4*)(P + base) = s;
}

// ---------------------------------------------------------------------------
// Avalanche: one workgroup per sample; state in registers.
// ---------------------------------------------------------------------------
template <int MODE, int NSPLIT>
__global__ __launch_bounds__(1024) void avalanche_kernel(const float* __restrict__ Pin,
                                                         const float* __restrict__ bias,
                                                         const void* __restrict__ connv,
                                                         float* __restrict__ out,
                                                         unsigned int* __restrict__ maxslot) {
  const int b = blockIdx.x;
  const int t = threadIdx.x;
  __shared__ unsigned long long mask[64];
  __shared__ int wincl[64];
  __shared__ int list[N_NODES];

  float4 s;
  if (MODE == 1) {
    const float4 bv = *(const float4*)(bias + t * 4);
    s = bv;
#pragma unroll
    for (int sp = 0; sp < NSPLIT; ++sp) {
      const float4 v = *(const float4*)(Pin + (size_t)sp * BATCH * N_NODES +
                                        (size_t)b * N_NODES + t * 4);
      s.x += v.x; s.y += v.y; s.z += v.z; s.w += v.w;
    }
  } else {
    s = *(const float4*)(Pin + (size_t)b * N_NODES + t * 4);
  }

  float total = 0.0f;

  for (int it = 0; it < 100; ++it) {
    const float v0 = s.x, v1 = s.y, v2 = s.z, v3 = s.w;
    unsigned int bits = 0;
    if (v0 > 1.0f) bits |= 1u;
    if (v1 > 1.0f) bits |= 2u;
    if (v2 > 1.0f) bits |= 4u;
    if (v3 > 1.0f) bits |= 8u;

    __syncthreads();
    if (t < 64) mask[t] = 0ULL;
    __syncthreads();
    if (bits) atomicOr(&mask[t >> 4], (unsigned long long)bits << ((t & 15) * 4));
    __syncthreads();

    if (t < 64) {
      int incl = __popcll(mask[t]);
#pragma unroll
      for (int d = 1; d < 64; d <<= 1) {
        const int y = __shfl_up(incl, d);
        if (t >= d) incl += y;
      }
      wincl[t] = incl;
    }
    __syncthreads();
    const int n = wincl[63];
    if (n == 0) break;  // sticky done: state frozen
    total += (float)n;

    if (t < 64) {
      unsigned long long m = mask[t];
      int o = wincl[t] - __popcll(m);
      while (m) {
        list[o++] = (t << 6) + __builtin_ctzll(m);
        m &= m - 1;
      }
    }
    __syncthreads();

    float4 a0 = make_float4(0.f, 0.f, 0.f, 0.f), a1 = a0, a2 = a0, a3 = a0;
    if (MODE == 1) {
      int idx = 0;
      for (; idx + 8 <= n; idx += 8) {
        const float4 c0 = conn_load4(connv, list[idx + 0], t);
        const float4 c1 = conn_load4(connv, list[idx + 1], t);
        const float4 c2 = conn_load4(connv, list[idx + 2], t);
        const float4 c3 = conn_load4(connv, list[idx + 3], t);
        const float4 c4 = conn_load4(connv, list[idx + 4], t);
        const float4 c5 = conn_load4(connv, list[idx + 5], t);
        const float4 c6 = conn_load4(connv, list[idx + 6], t);
        const float4 c7 = conn_load4(connv, list[idx + 7], t);
        a0.x += c0.x; a0.y += c0.y; a0.z += c0.z; a0.w += c0.w;
        a1.x += c1.x; a1.y += c1.y; a1.z += c1.z; a1.w += c1.w;
        a2.x += c2.x; a2.y += c2.y; a2.z += c2.z; a2.w += c2.w;
        a3.x += c3.x; a3.y += c3.y; a3.z += c3.z; a3.w += c3.w;
        a0.x += c4.x; a0.y += c4.y; a0.z += c4.z; a0.w += c4.w;
        a1.x += c5.x; a1.y += c5.y; a1.z += c5.z; a1.w += c5.w;
        a2.x += c6.x; a2.y += c6.y; a2.z += c6.z; a2.w += c6.w;
        a3.x += c7.x; a3.y += c7.y; a3.z += c7.z; a3.w += c7.w;
      }
      for (; idx < n; ++idx) {
        const float4 c = conn_load4(connv, list[idx], t);
        a0.x += c.x; a0.y += c.y; a0.z += c.z; a0.w += c.w;
      }
    } else {
      const float* conn = (const float*)connv;
      for (int idx = 0; idx < n; ++idx) {
        const int j = list[idx];
        a0.x += conn[(size_t)(t * 4 + 0) * N_NODES + j];
        a0.y += conn[(size_t)(t * 4 + 1) * N_NODES + j];
        a0.z += conn[(size_t)(t * 4 + 2) * N_NODES + j];
        a0.w += conn[(size_t)(t * 4 + 3) * N_NODES + j];
      }
    }
    const float sc = (MODE == 1) ? CONN_SCALE : 1.0f;
    const float4 acc = make_float4(((a0.x + a1.x) + (a2.x + a3.x)) * sc,
                                   ((a0.y + a1.y) + (a2.y + a3.y)) * sc,
                                   ((a0.z + a1.z) + (a2.z + a3.z)) * sc,
                                   ((a0.w + a1.w) + (a2.w + a3.w)) * sc);

    s.x = (v0 > 1.0f) ? 0.0f : 0.9f * v0 + acc.x;
    s.y = (v1 > 1.0f) ? 0.0f : 0.9f * v1 + acc.y;
    s.z = (v2 > 1.0f) ? 0.0f : 0.9f * v2 + acc.z;
    s.w = (v3 > 1.0f) ? 0.0f : 0.9f * v3 + acc.w;
  }

  *(float4*)(out + (size_t)b * N_NODES + t * 4) = s;
  if (t == 0) atomicMax(maxslot, __float_as_uint(total));  // totals >= 0
}

// ---------------------------------------------------------------------------
extern "C" void kernel_launch(void* const* d_in, const int* in_sizes, int n_in,
                              void* d_out, int out_size, void* d_ws, size_t ws_size,
                              hipStream_t stream) {
  const float* input = (const float*)d_in[0];  // [128,4096]
  const float* W     = (const float*)d_in[1];  // [4096,4096]
  const float* bias  = (const float*)d_in[2];  // [4096]
  const float* conn  = (const float*)d_in[3];  // [4096,4096]
  float* out = (float*)d_out;                  // [128*4096] state + [1] max_size

  const size_t aplane_bytes = (size_t)BATCH * N_NODES * 4;                       // 2 MB interleaved
  const size_t connT_bytes  = (size_t)N_NODES * N_NODES * CONN_ELEM_BYTES;       // 16/32 MB
  const size_t part_bytes   = (size_t)SPLITK * BATCH * N_NODES * sizeof(float);  // 32 MB
  unsigned int* maxslot = (unsigned int*)(out + (size_t)BATCH * N_NODES);

  if (ws_size >= aplane_bytes + connT_bytes + part_bytes) {
    _Float16* As = (_Float16*)d_ws;
    void* connT  = (char*)d_ws + aplane_bytes;
    float* part  = (float*)((char*)d_ws + aplane_bytes + connT_bytes);
    asplit_kernel<<<BATCH * N_NODES / 1024, 256, 0, stream>>>(input, As, maxslot);
    transpose_kernel<<<TRANS_BLOCKS, 256, 0, stream>>>(conn, connT);
    gemm_kernel<<<GEMM_BLOCKS, 256, 0, stream>>>(As, W, part);
    avalanche_kernel<1, SPLITK><<<BATCH, 1024, 0, stream>>>(part, bias, connT, out, maxslot);
  } else {
    // Fallback: no workspace — f32 GEMM into d_out, in-place bias, strided gather.
    proj_gemm_valu<<<dim3(N_NODES / 64, 1), 256, 0, stream>>>(input, W, out, maxslot);
    bias_inplace_kernel<<<BATCH * N_NODES / 1024, 256, 0, stream>>>(out, bias);
    avalanche_kernel<0, 1><<<BATCH, 1024, 0, stream>>>(out, nullptr, conn, out, maxslot);
  }
}

// Round 14
// 69.981 us; speedup vs baseline: 1.0195x; 1.0173x over previous
//
#include <hip/hip_runtime.h>

#define N_NODES 4096
#define BATCH 128
#define SPLITK 16
#define KCHUNK (N_NODES / SPLITK)  // 256
#define GEMM_BLOCKS 256            // 16 kidx x 16 row-groups
#define TRANS_BLOCKS (32 * 32)     // 128x128 tiles

typedef _Float16 f16x4 __attribute__((ext_vector_type(4)));
typedef _Float16 f16x8 __attribute__((ext_vector_type(8)));
typedef float f32x4 __attribute__((ext_vector_type(4)));
typedef unsigned int u32x4 __attribute__((ext_vector_type(4)));

// ---- async global->LDS DMA (dest = wave-uniform base + lane*16) ----
__device__ __forceinline__ void dma16(const void* g, void* l) {
#if defined(__has_builtin) && __has_builtin(__builtin_amdgcn_global_load_lds)
  __builtin_amdgcn_global_load_lds((const __attribute__((address_space(1))) void*)g,
                                   (__attribute__((address_space(3))) void*)l, 16, 0, 0);
#else
  *(u32x4*)l = *(const u32x4*)g;
#endif
}

// fp8 connT if the HW cvt builtins exist; else bf16 connT.
#if defined(__has_builtin)
#if __has_builtin(__builtin_amdgcn_cvt_f32_fp8) && __has_builtin(__builtin_amdgcn_cvt_pk_fp8_f32)
#define CONN_FP8 1
#endif
#endif
#ifndef CONN_FP8
#define CONN_FP8 0
#endif

#if CONN_FP8
#define CONN_ELEM_BYTES 1
#define CONN_SCALE (1.0f / 256.0f)
#else
#define CONN_ELEM_BYTES 2
#define CONN_SCALE 1.0f
#endif

__device__ __forceinline__ void conn_store4(void* out, size_t off, float4 v) {
#if CONN_FP8
  unsigned int p = __builtin_amdgcn_cvt_pk_fp8_f32(v.x * 256.0f, v.y * 256.0f, 0, false);
  p = (unsigned int)__builtin_amdgcn_cvt_pk_fp8_f32(v.z * 256.0f, v.w * 256.0f, (int)p, true);
  *(unsigned int*)((unsigned char*)out + off) = p;
#else
  const unsigned int ux = __float_as_uint(v.x), uy = __float_as_uint(v.y);
  const unsigned int uz = __float_as_uint(v.z), uw = __float_as_uint(v.w);
  ushort4 u;
  u.x = (unsigned short)((ux + 0x7FFFu + ((ux >> 16) & 1u)) >> 16);  // RNE
  u.y = (unsigned short)((uy + 0x7FFFu + ((uy >> 16) & 1u)) >> 16);
  u.z = (unsigned short)((uz + 0x7FFFu + ((uz >> 16) & 1u)) >> 16);
  u.w = (unsigned short)((uw + 0x7FFFu + ((uw >> 16) & 1u)) >> 16);
  *(ushort4*)((unsigned short*)out + off) = u;
#endif
}

__device__ __forceinline__ float4 conn_load4(const void* cT, int j, int t) {
#if CONN_FP8
  const unsigned int c = *(const unsigned int*)((const unsigned char*)cT + ((size_t)j << 12) + t * 4);
  return make_float4(__builtin_amdgcn_cvt_f32_fp8(c, 0), __builtin_amdgcn_cvt_f32_fp8(c, 1),
                     __builtin_amdgcn_cvt_f32_fp8(c, 2), __builtin_amdgcn_cvt_f32_fp8(c, 3));
#else
  const ushort4 c = *(const ushort4*)((const unsigned short*)cT + ((size_t)j << 12) + t * 4);
  return make_float4(__uint_as_float((unsigned int)c.x << 16),
                     __uint_as_float((unsigned int)c.y << 16),
                     __uint_as_float((unsigned int)c.z << 16),
                     __uint_as_float((unsigned int)c.w << 16));
#endif
}

// ---------------------------------------------------------------------------
// A-split, interleaved: per row m, per 32-k group: (hi[32] | lo[32]) f16,
// pre-scaled x256. Row = 8192 f16 = 16 KB. Also zeroes maxslot.
// ---------------------------------------------------------------------------
__global__ __launch_bounds__(256) void asplit_kernel(const float* __restrict__ in,
                                                     _Float16* __restrict__ As,
                                                     unsigned int* __restrict__ maxslot) {
  if (blockIdx.x == 0 && threadIdx.x == 0) *maxslot = 0u;
  const size_t idx = ((size_t)blockIdx.x * 256 + threadIdx.x) * 4;
  const int m = (int)(idx >> 12);
  const int k = (int)(idx & (N_NODES - 1));
  const float4 v = *(const float4*)(in + idx);
  f16x4 hi, lo;
  const float x0 = v.x * 256.f, x1 = v.y * 256.f, x2 = v.z * 256.f, x3 = v.w * 256.f;
  hi[0] = (_Float16)x0; lo[0] = (_Float16)(x0 - (float)hi[0]);
  hi[1] = (_Float16)x1; lo[1] = (_Float16)(x1 - (float)hi[1]);
  hi[2] = (_Float16)x2; lo[2] = (_Float16)(x2 - (float)hi[2]);
  hi[3] = (_Float16)x3; lo[3] = (_Float16)(x3 - (float)hi[3]);
  const size_t base = (size_t)m * 8192 + (size_t)(k >> 5) * 64 + (k & 31);
  *(f16x4*)(As + base) = hi;
  *(f16x4*)(As + base + 32) = lo;
}

// ---------------------------------------------------------------------------
// Transpose: connT[j][i] = enc(conn[i][j]), 128x128 tiles, full-line writes.
// ---------------------------------------------------------------------------
__global__ __launch_bounds__(256, 2) void transpose_kernel(const float* __restrict__ conn,
                                                           void* __restrict__ connT) {
  __shared__ float T[128][129];  // 66048 B
  const int tid = threadIdx.x;
  const int d = blockIdx.x;
  const int by = (d & 7) | ((d >> 8) << 3);  // XCD cluster on source rows
  const int bx = (d >> 3) & 31;

  const int rr = tid >> 4;        // 0..15
  const int c0 = (tid & 15) * 4;  // 0..60
#pragma unroll
  for (int pass = 0; pass < 8; ++pass) {
    const int r = pass * 16 + rr;
    const float* src = conn + (size_t)(by * 128 + r) * N_NODES + bx * 128;
    const float4 a = *(const float4*)(src + c0);
    const float4 b = *(const float4*)(src + c0 + 64);
    *(float4*)&T[r][c0] = a;
    *(float4*)&T[r][c0 + 64] = b;
  }
  __syncthreads();

  const int jr = tid >> 5;  // 0..7
  const int lc = tid & 31;  // 0..31
#pragma unroll
  for (int pass = 0; pass < 16; ++pass) {
    const int jj = pass * 8 + jr;
    float4 v;
    v.x = T[lc * 4 + 0][jj];
    v.y = T[lc * 4 + 1][jj];
    v.z = T[lc * 4 + 2][jj];
    v.w = T[lc * 4 + 3][jj];
    conn_store4(connT, (size_t)(bx * 128 + jj) * N_NODES + by * 128 + lc * 4, v);
  }
}

// ---------------------------------------------------------------------------
// GEMM, "A-resident W-stream": grid 256 = 16 kidx x 16 row-groups, 512 thr.
// Per block: stage A slice [128][256] (hi/lo f16, 128 KB LDS, XOR-swizzled)
// ONCE; then each wave independently streams 32 W rows (2 groups of 16):
// per kk, 4x16B W loads -> consumer-side split -> 16 ds_read_b128 + 48 MFMA.
// No barriers in the stream loop; W read exactly once, coalesced.
// P[kidx][m][n] = sum_{k in chunk kidx} A[m][k]*W[n][k].
// ---------------------------------------------------------------------------
__global__ __launch_bounds__(512, 1) void gemm_kernel(const _Float16* __restrict__ As,
                                                      const float* __restrict__ W,
                                                      float* __restrict__ P) {
  __shared__ _Float16 smA[128 * 512];  // 128 KB; row m = 1 KB = 8 kk-groups x (hi32|lo32)
  const int tid = threadIdx.x;
  const int bid = blockIdx.x;
  const int kidx = bid & 15;  // bid%8 == kidx%8 -> same-kidx blocks share an XCD (A L2-hot)
  const int G = bid >> 4;     // 0..15 row-group
  const int wave = tid >> 6, lane = tid & 63;
  const int g = lane >> 4, lrow = lane & 15;  // frag lane coords
  const int kb = kidx * KCHUNK;

  // ---- one-time A stage: 128 KB via 16 passes of 512x16B DMA (swizzled src)
#pragma unroll
  for (int p = 0; p < 16; ++p) {
    const int off = p * 8192 + tid * 16;  // linear LDS byte offset
    const int m = off >> 10;
    const int g64 = (off >> 4) & 63;
    const int kg = g64 >> 3, q = g64 & 7;
    dma16((const char*)As + (size_t)m * 16384 + (size_t)(kidx * 8 + kg) * 128 +
              ((q ^ (m & 7)) << 4),
          (char*)smA + off);
  }
  __syncthreads();  // drains DMA (vmcnt 0) + all waves see A

  // ---- W stream: this wave owns rows n0w .. n0w+31 of W (k-slice kb..kb+255)
  const int n0w = G * 256 + wave * 32;
  const float* Wl0 = W + (size_t)(n0w + lrow) * N_NODES + kb + g * 8;       // group 0
  const float* Wl1 = W + (size_t)(n0w + 16 + lrow) * N_NODES + kb + g * 8;  // group 1

  f32x4 acc[8][2] = {};

#pragma unroll
  for (int kk = 0; kk < 8; ++kk) {
    // W loads for both 16-row groups at this kk (4 x 16B per lane)
    const f32x4 b00 = *(const f32x4*)(Wl0 + kk * 32);
    const f32x4 b01 = *(const f32x4*)(Wl0 + kk * 32 + 4);
    const f32x4 b10 = *(const f32x4*)(Wl1 + kk * 32);
    const f32x4 b11 = *(const f32x4*)(Wl1 + kk * 32 + 4);
    f16x8 bh[2], bl[2];
#pragma unroll
    for (int j = 0; j < 4; ++j) {
      float x;
      _Float16 h;
      x = b00[j] * 64.f; h = (_Float16)x; bh[0][j] = h; bl[0][j] = (_Float16)(x - (float)h);
      x = b01[j] * 64.f; h = (_Float16)x; bh[0][4 + j] = h; bl[0][4 + j] = (_Float16)(x - (float)h);
      x = b10[j] * 64.f; h = (_Float16)x; bh[1][j] = h; bl[1][j] = (_Float16)(x - (float)h);
      x = b11[j] * 64.f; h = (_Float16)x; bh[1][4 + j] = h; bl[1][4 + j] = (_Float16)(x - (float)h);
    }
#pragma unroll
    for (int fm = 0; fm < 8; ++fm) {
      const int m = fm * 16 + lrow;
      const char* ab = (const char*)smA + m * 1024 + kk * 128;
      const int s = m & 7;
      const f16x8 ah = *(const f16x8*)(ab + ((g ^ s) << 4));
      const f16x8 al = *(const f16x8*)(ab + (((4 + g) ^ s) << 4));
#pragma unroll
      for (int fn = 0; fn < 2; ++fn) {
        acc[fm][fn] = __builtin_amdgcn_mfma_f32_16x16x32_f16(ah, bh[fn], acc[fm][fn], 0, 0, 0);
        acc[fm][fn] = __builtin_amdgcn_mfma_f32_16x16x32_f16(ah, bl[fn], acc[fm][fn], 0, 0, 0);
        acc[fm][fn] = __builtin_amdgcn_mfma_f32_16x16x32_f16(al, bh[fn], acc[fm][fn], 0, 0, 0);
      }
    }
  }

  // epilogue: D row(m-dim) = g*4 + reg, col(n-dim) = lrow (HW-verified layout)
  constexpr float INV = 1.0f / 16384.0f;  // 1/(256*64)
  float* Pb = P + (size_t)kidx * BATCH * N_NODES;
#pragma unroll
  for (int fm = 0; fm < 8; ++fm)
#pragma unroll
    for (int fn = 0; fn < 2; ++fn) {
      const int n = n0w + fn * 16 + lrow;
#pragma unroll
      for (int reg = 0; reg < 4; ++reg) {
        const int m = fm * 16 + g * 4 + reg;
        Pb[(size_t)m * N_NODES + n] = acc[fm][fn][reg] * INV;
      }
    }
}

// ---------------------------------------------------------------------------
// Fallback-only f32 VALU GEMM (no workspace)
// ---------------------------------------------------------------------------
__global__ __launch_bounds__(256) void proj_gemm_valu(const float* __restrict__ A,
                                                      const float* __restrict__ W,
                                                      float* __restrict__ P,
                                                      unsigned int* __restrict__ maxslot) {
  if (blockIdx.x == 0 && threadIdx.x == 0) *maxslot = 0u;
  __shared__ float Asb[16][132];
  __shared__ float Bsb[16][68];
  const int tid = threadIdx.x;
  const int n0 = blockIdx.x * 64;
  const int tx = tid & 15, ty = tid >> 4;
  const int arow = tid >> 1, acol = (tid & 1) * 8;
  const int brow = tid >> 2, bcol = (tid & 3) * 4;
  float acc[2][4][4] = {};
  const float* Aptr = A + (size_t)arow * N_NODES + acol;
  const float* Wptr = W + (size_t)(n0 + brow) * N_NODES + bcol;
  for (int k0 = 0; k0 < N_NODES; k0 += 16) {
    const float4 a0 = *(const float4*)(Aptr + k0);
    const float4 a1 = *(const float4*)(Aptr + k0 + 4);
    const float4 bv = *(const float4*)(Wptr + k0);
    __syncthreads();
    Asb[acol + 0][arow] = a0.x; Asb[acol + 1][arow] = a0.y;
    Asb[acol + 2][arow] = a0.z; Asb[acol + 3][arow] = a0.w;
    Asb[acol + 4][arow] = a1.x; Asb[acol + 5][arow] = a1.y;
    Asb[acol + 6][arow] = a1.z; Asb[acol + 7][arow] = a1.w;
    Bsb[bcol + 0][brow] = bv.x; Bsb[bcol + 1][brow] = bv.y;
    Bsb[bcol + 2][brow] = bv.z; Bsb[bcol + 3][brow] = bv.w;
    __syncthreads();
#pragma unroll
    for (int kk = 0; kk < 16; ++kk) {
      const float4 av0 = *(const float4*)&Asb[kk][ty * 4];
      const float4 av1 = *(const float4*)&Asb[kk][64 + ty * 4];
      const float4 bv4 = *(const float4*)&Bsb[kk][tx * 4];
      const float am[8] = {av0.x, av0.y, av0.z, av0.w, av1.x, av1.y, av1.z, av1.w};
      const float bn[4] = {bv4.x, bv4.y, bv4.z, bv4.w};
#pragma unroll
      for (int i2 = 0; i2 < 2; ++i2)
#pragma unroll
        for (int i = 0; i < 4; ++i)
#pragma unroll
          for (int j = 0; j < 4; ++j)
            acc[i2][i][j] += am[i2 * 4 + i] * bn[j];
    }
  }
#pragma unroll
  for (int i2 = 0; i2 < 2; ++i2)
#pragma unroll
    for (int i = 0; i < 4; ++i) {
      const int m = i2 * 64 + ty * 4 + i;
      *(float4*)(P + (size_t)m * N_NODES + n0 + tx * 4) =
          make_float4(acc[i2][i][0], acc[i2][i][1], acc[i2][i][2], acc[i2][i][3]);
    }
}

__global__ __launch_bounds__(256) void bias_inplace_kernel(float* __restrict__ P,
                                                           const float* __restrict__ bias) {
  const size_t base = ((size_t)blockIdx.x * 256 + threadIdx.x) * 4;
  const int n = (int)(base & (N_NODES - 1));
  float4 s = *(const float4*)(P + base);
  const float4 bv = *(const float4*)(bias + n);
  s.x += bv.x; s.y += bv.y; s.z += bv.z; s.w += bv.w;
  *(float4*)(P + base) = s;
}

// ---------------------------------------------------------------------------
// Avalanche: one workgroup per sample; state in registers.
// ---------------------------------------------------------------------------
template <int MODE, int NSPLIT>
__global__ __launch_bounds__(1024) void avalanche_kernel(const float* __restrict__ Pin,
                                                         const float* __restrict__ bias,
                                                         const void* __restrict__ connv,
                                                         float* __restrict__ out,
                                                         unsigned int* __restrict__ maxslot) {
  const int b = blockIdx.x;
  const int t = threadIdx.x;
  __shared__ unsigned long long mask[64];
  __shared__ int wincl[64];
  __shared__ int list[N_NODES];

  float4 s;
  if (MODE == 1) {
    const float4 bv = *(const float4*)(bias + t * 4);
    s = bv;
#pragma unroll
    for (int sp = 0; sp < NSPLIT; ++sp) {
      const float4 v = *(const float4*)(Pin + (size_t)sp * BATCH * N_NODES +
                                        (size_t)b * N_NODES + t * 4);
      s.x += v.x; s.y += v.y; s.z += v.z; s.w += v.w;
    }
  } else {
    s = *(const float4*)(Pin + (size_t)b * N_NODES + t * 4);
  }

  float total = 0.0f;

  for (int it = 0; it < 100; ++it) {
    const float v0 = s.x, v1 = s.y, v2 = s.z, v3 = s.w;
    unsigned int bits = 0;
    if (v0 > 1.0f) bits |= 1u;
    if (v1 > 1.0f) bits |= 2u;
    if (v2 > 1.0f) bits |= 4u;
    if (v3 > 1.0f) bits |= 8u;

    __syncthreads();
    if (t < 64) mask[t] = 0ULL;
    __syncthreads();
    if (bits) atomicOr(&mask[t >> 4], (unsigned long long)bits << ((t & 15) * 4));
    __syncthreads();

    if (t < 64) {
      int incl = __popcll(mask[t]);
#pragma unroll
      for (int d = 1; d < 64; d <<= 1) {
        const int y = __shfl_up(incl, d);
        if (t >= d) incl += y;
      }
      wincl[t] = incl;
    }
    __syncthreads();
    const int n = wincl[63];
    if (n == 0) break;  // sticky done: state frozen
    total += (float)n;

    if (t < 64) {
      unsigned long long m = mask[t];
      int o = wincl[t] - __popcll(m);
      while (m) {
        list[o++] = (t << 6) + __builtin_ctzll(m);
        m &= m - 1;
      }
    }
    __syncthreads();

    float4 a0 = make_float4(0.f, 0.f, 0.f, 0.f), a1 = a0, a2 = a0, a3 = a0;
    if (MODE == 1) {
      int idx = 0;
      for (; idx + 8 <= n; idx += 8) {
        const float4 c0 = conn_load4(connv, list[idx + 0], t);
        const float4 c1 = conn_load4(connv, list[idx + 1], t);
        const float4 c2 = conn_load4(connv, list[idx + 2], t);
        const float4 c3 = conn_load4(connv, list[idx + 3], t);
        const float4 c4 = conn_load4(connv, list[idx + 4], t);
        const float4 c5 = conn_load4(connv, list[idx + 5], t);
        const float4 c6 = conn_load4(connv, list[idx + 6], t);
        const float4 c7 = conn_load4(connv, list[idx + 7], t);
        a0.x += c0.x; a0.y += c0.y; a0.z += c0.z; a0.w += c0.w;
        a1.x += c1.x; a1.y += c1.y; a1.z += c1.z; a1.w += c1.w;
        a2.x += c2.x; a2.y += c2.y; a2.z += c2.z; a2.w += c2.w;
        a3.x += c3.x; a3.y += c3.y; a3.z += c3.z; a3.w += c3.w;
        a0.x += c4.x; a0.y += c4.y; a0.z += c4.z; a0.w += c4.w;
        a1.x += c5.x; a1.y += c5.y; a1.z += c5.z; a1.w += c5.w;
        a2.x += c6.x; a2.y += c6.y; a2.z += c6.z; a2.w += c6.w;
        a3.x += c7.x; a3.y += c7.y; a3.z += c7.z; a3.w += c7.w;
      }
      for (; idx < n; ++idx) {
        const float4 c = conn_load4(connv, list[idx], t);
        a0.x += c.x; a0.y += c.y; a0.z += c.z; a0.w += c.w;
      }
    } else {
      const float* conn = (const float*)connv;
      for (int idx = 0; idx < n; ++idx) {
        const int j = list[idx];
        a0.x += conn[(size_t)(t * 4 + 0) * N_NODES + j];
        a0.y += conn[(size_t)(t * 4 + 1) * N_NODES + j];
        a0.z += conn[(size_t)(t * 4 + 2) * N_NODES + j];
        a0.w += conn[(size_t)(t * 4 + 3) * N_NODES + j];
      }
    }
    const float sc = (MODE == 1) ? CONN_SCALE : 1.0f;
    const float4 acc = make_float4(((a0.x + a1.x) + (a2.x + a3.x)) * sc,
                                   ((a0.y + a1.y) + (a2.y + a3.y)) * sc,
                                   ((a0.z + a1.z) + (a2.z + a3.z)) * sc,
                                   ((a0.w + a1.w) + (a2.w + a3.w)) * sc);

    s.x = (v0 > 1.0f) ? 0.0f : 0.9f * v0 + acc.x;
    s.y = (v1 > 1.0f) ? 0.0f : 0.9f * v1 + acc.y;
    s.z = (v2 > 1.0f) ? 0.0f : 0.9f * v2 + acc.z;
    s.w = (v3 > 1.0f) ? 0.0f : 0.9f * v3 + acc.w;
  }

  *(float4*)(out + (size_t)b * N_NODES + t * 4) = s;
  if (t == 0) atomicMax(maxslot, __float_as_uint(total));  // totals >= 0
}

// ---------------------------------------------------------------------------
extern "C" void kernel_launch(void* const* d_in, const int* in_sizes, int n_in,
                              void* d_out, int out_size, void* d_ws, size_t ws_size,
                              hipStream_t stream) {
  const float* input = (const float*)d_in[0];  // [128,4096]
  const float* W     = (const float*)d_in[1];  // [4096,4096]
  const float* bias  = (const float*)d_in[2];  // [4096]
  const float* conn  = (const float*)d_in[3];  // [4096,4096]
  float* out = (float*)d_out;                  // [128*4096] state + [1] max_size

  const size_t aplane_bytes = (size_t)BATCH * N_NODES * 4;                       // 2 MB interleaved
  const size_t connT_bytes  = (size_t)N_NODES * N_NODES * CONN_ELEM_BYTES;       // 16/32 MB
  const size_t part_bytes   = (size_t)SPLITK * BATCH * N_NODES * sizeof(float);  // 32 MB
  unsigned int* maxslot = (unsigned int*)(out + (size_t)BATCH * N_NODES);

  if (ws_size >= aplane_bytes + connT_bytes + part_bytes) {
    _Float16* As = (_Float16*)d_ws;
    void* connT  = (char*)d_ws + aplane_bytes;
    float* part  = (float*)((char*)d_ws + aplane_bytes + connT_bytes);
    asplit_kernel<<<BATCH * N_NODES / 1024, 256, 0, stream>>>(input, As, maxslot);
    transpose_kernel<<<TRANS_BLOCKS, 256, 0, stream>>>(conn, connT);
    gemm_kernel<<<GEMM_BLOCKS, 512, 0, stream>>>(As, W, part);
    avalanche_kernel<1, SPLITK><<<BATCH, 1024, 0, stream>>>(part, bias, connT, out, maxslot);
  } else {
    // Fallback: no workspace — f32 GEMM into d_out, in-place bias, strided gather.
    proj_gemm_valu<<<dim3(N_NODES / 64, 1), 256, 0, stream>>>(input, W, out, maxslot);
    bias_inplace_kernel<<<BATCH * N_NODES / 1024, 256, 0, stream>>>(out, bias);
    avalanche_kernel<0, 1><<<BATCH, 1024, 0, stream>>>(out, nullptr, conn, out, maxslot);
  }
}